// Round 12
// baseline (114.584 us; speedup 1.0000x reference)
//
#include <hip/hip_runtime.h>
#include <hip/hip_bf16.h>

#define HWP 9216   // H*W
#define HH  96
#define WW  96
#define CC  256    // Cin == Cout
#define NB  2

typedef __attribute__((ext_vector_type(8))) short bf16x8;
typedef __attribute__((ext_vector_type(4))) float f32x4;

__device__ inline unsigned short f2bf(float f) {
  union { __hip_bfloat16 h; unsigned short u; } cvt;
  cvt.h = __float2bfloat16(f);
  return cvt.u;
}
__device__ inline float bf_lo(unsigned int u) { return __uint_as_float(u << 16); }
__device__ inline float bf_hi(unsigned int u) { return __uint_as_float(u & 0xffff0000u); }
// LDS anti-bank-conflict padding (R18): +4 floats every 64 -> 2-way (free).
__device__ inline int padc(int c) { return c + ((c >> 6) << 2); }

// ====================== R21 ======================
// R19/R20 banked (113.2): k_main BN-split + partial offs0/offs1. Budget:
// fixed fills ~70us, k_main ~10us (floor ~5-6), k_gather ~16-20us (floor
// ~11-12, L2-latency-bound; 9 blocks/CU x 15KB gather rows thrash 32KB L1).
// R21 (k_gather only): remove the decode block-barrier from the critical
// path. (a) offs loads issued at kernel top (lanes hl<9; each HALF-WAVE
// decodes its own pixel's 9 taps, kk=hl); (b) dvs staged with COALESCED
// loads and its single __syncthreads placed BEFORE the decode (barrier
// overlaps offs latency); (c) decode writes Wt[ip][*]/Ad[ip][*] consumed
// only by the same wave -> __threadfence_block() (lgkmcnt fence; CDNA waves
// are single-PC lockstep) instead of s_barrier. Each wave starts corner
// loads as soon as ITS decode finishes. Bit-identical output.
// PITFALLS: R12 cooperative grid.sync broken under graph capture; R17 no
// per-block offs recompute; R6/R7 no MFMA-frag reg-prefetch; R9 no BK=64;
// R6 no launch-bounds min-wave; R4 no nontemporal out stores; R8 no VGPR
// blowup in gather.

__global__ __launch_bounds__(256) void k_main(const float* __restrict__ x,
                                              const float* __restrict__ pw_w,
                                              const float* __restrict__ off_w,
                                              const float* __restrict__ off_b,
                                              unsigned short* __restrict__ xpb,
                                              float* __restrict__ offs0,
                                              float* __restrict__ offs1) {
  __shared__ unsigned short As[2][32 * 40];    // [pix][k] dbuf
  __shared__ unsigned short Bs[2][128 * 40];   // [n][k] dbuf; Bs[0] reused as Cs

  // XCD-aligned decode: g -> (e, nh, b, m); both ch-halves of a strip share e
  int g    = blockIdx.x;         // 0..1151
  int e    = g & 7;
  int idx  = g >> 3;             // 0..143
  int nh   = idx & 1;            // channel half
  int idx2 = idx >> 1;           // 0..71
  int b    = idx2 / 36;
  int m    = idx2 - b * 36;      // 0..35
  int pix0 = (e * 36 + m) * 32;  // local pixel within batch
  int nb0  = nh * 128;           // output-channel base

  int t    = threadIdx.x;
  int lane = t & 63;
  int w    = t >> 6;
  int mw  = (w & 1) * 16;        // wave pixel tile
  int nwl = (w >> 1) * 64;       // wave channel quarter (of 128)
  int r = lane & 15, q = lane >> 4;

  f32x4 acc[4] = {};

  const float* xg = x + (size_t)b * CC * HWP + pix0;
  int sc = t >> 3;           // channel within 32-chunk
  int sp = (t & 7) * 4;      // pixel offset
  int nB = t >> 1;           // B row (0..127)
  int kh = (t & 1) * 16;     // B k-offset

  // ---- prologue: stage K-step 0 into buf 0 (B converted inline from f32)
  {
    f32x4 xv = *(const f32x4*)(xg + (size_t)sc * HWP + sp);
    As[0][(sp + 0) * 40 + sc] = f2bf(xv.x);
    As[0][(sp + 1) * 40 + sc] = f2bf(xv.y);
    As[0][(sp + 2) * 40 + sc] = f2bf(xv.z);
    As[0][(sp + 3) * 40 + sc] = f2bf(xv.w);
    const float* wp = pw_w + (size_t)(nb0 + nB) * 256 + kh;
#pragma unroll
    for (int h = 0; h < 2; ++h) {
      float4 w0 = *(const float4*)(wp + h * 8);
      float4 w1 = *(const float4*)(wp + h * 8 + 4);
      union { ushort4 s[2]; uint4 q4; } pk;
      pk.s[0] = make_ushort4(f2bf(w0.x), f2bf(w0.y), f2bf(w0.z), f2bf(w0.w));
      pk.s[1] = make_ushort4(f2bf(w1.x), f2bf(w1.y), f2bf(w1.z), f2bf(w1.w));
      *(uint4*)&Bs[0][nB * 40 + kh + h * 8] = pk.q4;
    }
  }
  __syncthreads();

  // ---- main loop: 1 barrier per K-step, prefetch t+1 overlapped with MFMA(t)
  for (int kt = 0; kt < 8; ++kt) {
    int cur = kt & 1;
    f32x4 xv;
    float4 b0[2], b1[2];
    bool pre = (kt < 7);
    if (pre) {
      int k0 = (kt + 1) * 32;
      xv = *(const f32x4*)(xg + (size_t)(k0 + sc) * HWP + sp);
      const float* wp = pw_w + (size_t)(nb0 + nB) * 256 + k0 + kh;
#pragma unroll
      for (int h = 0; h < 2; ++h) {
        b0[h] = *(const float4*)(wp + h * 8);
        b1[h] = *(const float4*)(wp + h * 8 + 4);
      }
    }
    bf16x8 a = *(const bf16x8*)&As[cur][(mw + r) * 40 + q * 8];
#pragma unroll
    for (int nt = 0; nt < 4; ++nt) {
      bf16x8 bb = *(const bf16x8*)&Bs[cur][(nwl + nt * 16 + r) * 40 + q * 8];
      acc[nt] = __builtin_amdgcn_mfma_f32_16x16x32_bf16(a, bb, acc[nt], 0, 0, 0);
    }
    if (pre) {
      int nx = cur ^ 1;
      As[nx][(sp + 0) * 40 + sc] = f2bf(xv.x);
      As[nx][(sp + 1) * 40 + sc] = f2bf(xv.y);
      As[nx][(sp + 2) * 40 + sc] = f2bf(xv.z);
      As[nx][(sp + 3) * 40 + sc] = f2bf(xv.w);
#pragma unroll
      for (int h = 0; h < 2; ++h) {
        union { ushort4 s[2]; uint4 q4; } pk;
        pk.s[0] = make_ushort4(f2bf(b0[h].x), f2bf(b0[h].y), f2bf(b0[h].z), f2bf(b0[h].w));
        pk.s[1] = make_ushort4(f2bf(b1[h].x), f2bf(b1[h].y), f2bf(b1[h].z), f2bf(b1[h].w));
        *(uint4*)&Bs[nx][nB * 40 + kh + h * 8] = pk.q4;
      }
    }
    __syncthreads();
  }

  // Cs aliases Bs[0]: last K-step read buf 1; final sync drained buf 0 reads.
  unsigned short* Cs = &Bs[0][0];   // [32][136] bf16 (4352 shorts <= 5120)

  // C/D: col = lane&15 (ch), row = q*4+rr (pix) -> Cs[pix][ch] bf16
#pragma unroll
  for (int nt = 0; nt < 4; ++nt)
#pragma unroll
    for (int rr = 0; rr < 4; ++rr)
      Cs[(mw + q * 4 + rr) * 136 + nwl + nt * 16 + r] = f2bf(acc[nt][rr]);
  __syncthreads();

  // write xpb coalesced: 32 B contiguous per thread (128-ch half)
  {
    int pix = t >> 3, c16 = (t & 7) * 16;
    unsigned short* o = xpb + ((size_t)b * HWP + pix0 + pix) * CC + nb0 + c16;
    *(uint4*)(o + 0) = *(const uint4*)&Cs[pix * 136 + c16 + 0];
    *(uint4*)(o + 8) = *(const uint4*)&Cs[pix * 136 + c16 + 8];
  }

  // offs PARTIAL epilogue over this block's K=128 slice (4 K-steps):
  // offs_h[pix, o] = sum_{c in half} Cs[pix][c] * off_w[o][nb0+c] (+off_b if nh==0)
  {
    float* offs_h = nh ? offs1 : offs0;
    int mw2 = (w & 1) * 16;    // pixel tile
    int nw2 = (w >> 1) * 16;   // o tile (0 or 16)
    int row = nw2 + r;
    f32x4 oacc = {};
#pragma unroll
    for (int ks = 0; ks < 128; ks += 32) {
      bf16x8 a = *(const bf16x8*)&Cs[(mw2 + r) * 136 + ks + q * 8];
      bf16x8 bb = {};
      if (row < 18) {
        const float* wp = off_w + row * 256 + nb0 + ks + q * 8;
        float4 w0 = *(const float4*)wp;
        float4 w1 = *(const float4*)(wp + 4);
        union { unsigned short u[8]; bf16x8 v; } pk;
        pk.u[0] = f2bf(w0.x); pk.u[1] = f2bf(w0.y); pk.u[2] = f2bf(w0.z); pk.u[3] = f2bf(w0.w);
        pk.u[4] = f2bf(w1.x); pk.u[5] = f2bf(w1.y); pk.u[6] = f2bf(w1.z); pk.u[7] = f2bf(w1.w);
        bb = pk.v;
      }
      oacc = __builtin_amdgcn_mfma_f32_16x16x32_bf16(a, bb, oacc, 0, 0, 0);
    }
    if (row < 18) {
      float ob = nh ? 0.f : off_b[row];
      size_t base = ((size_t)b * HWP + pix0 + mw2 + q * 4) * 20 + row;
#pragma unroll
      for (int rr = 0; rr < 4; ++rr)
        offs_h[base + (size_t)rr * 20] = oacc[rr] + ob;
    }
  }
}

// ---- gather + depthwise: R18 structure (8 px/block, half-wave pixel split,
// uint4 corner loads, padc LDS) + R21 wave-local decode (no decode barrier).
__global__ __launch_bounds__(256) void k_gather(const unsigned short* __restrict__ xp,
                                                const float* __restrict__ offs0,
                                                const float* __restrict__ offs1,
                                                const float* __restrict__ dw_w,
                                                float* __restrict__ out) {
  __shared__ float Cs[8][268];    // padc-padded (256 + 12)
  __shared__ float4 Wt[8][9];     // bilinear weights per (pixel, tap)
  __shared__ int4   Ad[8][9];     // corner row byte-offsets per (pixel, tap)
  __shared__ float  dvs[9][268];  // dw_w transposed [tap][ch], padc-padded

  // XCD-aligned decode: g -> (e, b, m2); chunk c = e*144 + m2 (8 px each)
  int g   = blockIdx.x;          // 0..2303
  int e   = g & 7;
  int idx = g >> 3;              // 0..287
  int b   = idx / 144;
  int m2  = idx - b * 144;       // 0..143
  int c   = e * 144 + m2;        // 0..1151
  int hw0 = c * 8;               // pixel within batch
  int pix0 = b * HWP + hw0;      // global pixel

  int wave = threadIdx.x >> 6;
  int lane = threadIdx.x & 63;
  int hp   = lane >> 5;          // half-wave pixel select (0/1)
  int hl   = lane & 31;          // lane within half-wave
  int ip   = wave * 2 + hp;      // this lane's pixel 0..7
  int c0   = hl * 8;             // this lane's 8-channel base
  int pc0  = padc(c0);           // padded LDS index (16B-aligned)

  const unsigned short* xb = xp + (size_t)b * HWP * CC;
  const float* opb0 = offs0 + (size_t)pix0 * 20;
  const float* opb1 = offs1 + (size_t)pix0 * 20;

  // ---- issue offs loads FIRST (lanes hl<9: this half-wave's pixel, tap hl)
  float2 oa = make_float2(0.f, 0.f), ob2 = make_float2(0.f, 0.f);
  if (hl < 9) {
    oa  = *(const float2*)(opb0 + ip * 20 + 2 * hl);
    ob2 = *(const float2*)(opb1 + ip * 20 + 2 * hl);
  }

  // ---- stage dvs with coalesced loads: thread t handles dw_w[t + j*256]
  {
    int t = threadIdx.x;
#pragma unroll
    for (int j = 0; j < 9; ++j) {
      int i = t + j * 256;           // 0..2303
      int ch = i / 9, kk = i - ch * 9;
      dvs[kk][padc(ch)] = dw_w[i];
    }
  }
  __syncthreads();   // dvs ready; overlaps the offs-load latency above

  // ---- wave-local decode: lane hl<9 decodes tap hl of its pixel ip.
  // Producer lanes and consumers are the SAME wave (each half-wave reads only
  // Wt/Ad[ip][*]) -> threadfence_block (lgkmcnt fence) suffices, no s_barrier.
  if (hl < 9) {
    int kk = hl;
    int hw = hw0 + ip;
    int h = hw / WW;
    int wq = hw - h * WW;
    float y = (float)(h + kk / 3 - 1) + oa.x + ob2.x;
    float x = (float)(wq + kk % 3 - 1) + oa.y + ob2.y;
    float y0f = floorf(y), x0f = floorf(x);
    float fy = y - y0f, fx = x - x0f;
    int y0 = (int)y0f, x0 = (int)x0f;
    int y1 = y0 + 1, x1 = x0 + 1;
    bool vy0 = (y0 >= 0) & (y0 < HH);
    bool vy1 = (y1 >= 0) & (y1 < HH);
    bool vx0 = (x0 >= 0) & (x0 < WW);
    bool vx1 = (x1 >= 0) & (x1 < WW);
    int y0c = y0 < 0 ? 0 : (y0 > HH - 1 ? HH - 1 : y0);
    int y1c = y1 < 0 ? 0 : (y1 > HH - 1 ? HH - 1 : y1);
    int x0c = x0 < 0 ? 0 : (x0 > WW - 1 ? WW - 1 : x0);
    int x1c = x1 < 0 ? 0 : (x1 > WW - 1 ? WW - 1 : x1);
    Wt[ip][kk] = make_float4(
        (1.f - fy) * (1.f - fx) * ((vy0 && vx0) ? 1.f : 0.f),
        (1.f - fy) * fx         * ((vy0 && vx1) ? 1.f : 0.f),
        fy * (1.f - fx)         * ((vy1 && vx0) ? 1.f : 0.f),
        fy * fx                 * ((vy1 && vx1) ? 1.f : 0.f));
    Ad[ip][kk] = make_int4((y0c * WW + x0c) * (CC * 2), (y0c * WW + x1c) * (CC * 2),
                           (y1c * WW + x0c) * (CC * 2), (y1c * WW + x1c) * (CC * 2));
  }
  __threadfence_block();   // wave-local LDS visibility (lockstep wave + fence)

  // ---- main loop: 4 uint4 corner loads per tap; unpack + FMA only.
  const char* xbc = (const char*)xb;
  unsigned lb = (unsigned)(hl * 16);   // this lane's 8-channel byte offset

  float acc[8] = {};
#pragma unroll
  for (int kk = 0; kk < 9; ++kk) {
    float4 dv0 = *(const float4*)&dvs[kk][pc0];
    float4 dv1 = *(const float4*)&dvs[kk][pc0 + 4];
    float4 wv = Wt[ip][kk];
    int4 av = Ad[ip][kk];
    uint4 u00 = *(const uint4*)(xbc + ((unsigned)av.x + lb));
    uint4 u01 = *(const uint4*)(xbc + ((unsigned)av.y + lb));
    uint4 u10 = *(const uint4*)(xbc + ((unsigned)av.z + lb));
    uint4 u11 = *(const uint4*)(xbc + ((unsigned)av.w + lb));
    const unsigned* p00 = (const unsigned*)&u00;
    const unsigned* p01 = (const unsigned*)&u01;
    const unsigned* p10 = (const unsigned*)&u10;
    const unsigned* p11 = (const unsigned*)&u11;
    float dvv[8] = {dv0.x, dv0.y, dv0.z, dv0.w, dv1.x, dv1.y, dv1.z, dv1.w};
#pragma unroll
    for (int j = 0; j < 4; ++j) {
      unsigned w00 = p00[j], w01 = p01[j], w10 = p10[j], w11 = p11[j];
      float slo = wv.x * bf_lo(w00) + wv.y * bf_lo(w01) + wv.z * bf_lo(w10) + wv.w * bf_lo(w11);
      float shi = wv.x * bf_hi(w00) + wv.y * bf_hi(w01) + wv.z * bf_hi(w10) + wv.w * bf_hi(w11);
      acc[2 * j]     += dvv[2 * j]     * slo;
      acc[2 * j + 1] += dvv[2 * j + 1] * shi;
    }
  }
  *(float4*)&Cs[ip][pc0]     = make_float4(acc[0], acc[1], acc[2], acc[3]);
  *(float4*)&Cs[ip][pc0 + 4] = make_float4(acc[4], acc[5], acc[6], acc[7]);
  __syncthreads();
  // write-out: thread t = channel, 8 consecutive pixels = 32 B contiguous.
  int ch = threadIdx.x;
  int pch = padc(ch);
  float* ob = out + (size_t)b * CC * HWP + (size_t)ch * HWP + hw0;
  *(float4*)(ob + 0) = make_float4(Cs[0][pch], Cs[1][pch], Cs[2][pch], Cs[3][pch]);
  *(float4*)(ob + 4) = make_float4(Cs[4][pch], Cs[5][pch], Cs[6][pch], Cs[7][pch]);
}

extern "C" void kernel_launch(void* const* d_in, const int* in_sizes, int n_in,
                              void* d_out, int out_size, void* d_ws, size_t ws_size,
                              hipStream_t stream) {
  (void)in_sizes; (void)n_in; (void)out_size; (void)ws_size;
  const float* x     = (const float*)d_in[0];
  const float* pw_w  = (const float*)d_in[1];
  const float* off_w = (const float*)d_in[2];
  const float* off_b = (const float*)d_in[3];
  const float* dw_w  = (const float*)d_in[4];
  float* out = (float*)d_out;

  char* ws = (char*)d_ws;
  unsigned short* xpb = (unsigned short*)ws;             // B*HW*C bf16 = 9,437,184 B
  float* offs0 = (float*)(ws + 9437184);                 // B*HW*20 f32 = 1,474,560 B
  float* offs1 = (float*)(ws + 10911744);                // B*HW*20 f32 = 1,474,560 B

  k_main  <<<1152, 256, 0, stream>>>(x, pw_w, off_w, off_b, xpb, offs0, offs1);
  k_gather<<<2304, 256, 0, stream>>>(xpb, offs0, offs1, dw_w, out);
}

// Round 13
// 113.727 us; speedup vs baseline: 1.0075x; 1.0075x over previous
//
#include <hip/hip_runtime.h>
#include <hip/hip_bf16.h>

#define HWP 9216   // H*W
#define HH  96
#define WW  96
#define CC  256    // Cin == Cout
#define NB  2

typedef __attribute__((ext_vector_type(8))) short bf16x8;
typedef __attribute__((ext_vector_type(4))) float f32x4;

__device__ inline unsigned short f2bf(float f) {
  union { __hip_bfloat16 h; unsigned short u; } cvt;
  cvt.h = __float2bfloat16(f);
  return cvt.u;
}
__device__ inline float bf_lo(unsigned int u) { return __uint_as_float(u << 16); }
__device__ inline float bf_hi(unsigned int u) { return __uint_as_float(u & 0xffff0000u); }
// LDS anti-bank-conflict padding (R18): +4 floats every 64 -> 2-way (free).
__device__ inline int padc(int c) { return c + ((c >> 6) << 2); }

// ====================== R22 ======================
// R21 POST-MORTEM (114.6, slight regression): wave-local decode added
// divergence (9/32 lanes) + VALU (div/mod staging) and the decode barrier
// was NOT on the critical path. PITFALL: in this gather the compiler already
// overlaps offs loads with staging; restructuring for it costs more than it
// buys. Three consecutive gather micro-opts inside +-1.5us (R18 +0.9,
// R21 -1.4): gather is at a practical plateau — full occupancy (32 waves/CU
// cap), bound by L1/L2 gather-transaction throughput near its ~10-12us floor.
// R22 = revert to R19/R20 (113.2 best) + epsilon hoist: offs float2 loads
// issued before dvs staging (latency overlap), same math, bit-identical.
// Budget: fixed fills ~70us, k_main ~10us (floor ~6), k_gather ~16-18us
// (floor ~10-12). Remaining lever = data-dependent corner dedup (high-risk).
// PITFALLS: R12 cooperative grid.sync broken under graph capture; R17 no
// per-block offs recompute; R6/R7 no MFMA-frag reg-prefetch; R9 no BK=64;
// R6 no launch-bounds min-wave; R4 no nontemporal out stores; R8 no VGPR
// blowup in gather; R21 no wave-local decode.

__global__ __launch_bounds__(256) void k_main(const float* __restrict__ x,
                                              const float* __restrict__ pw_w,
                                              const float* __restrict__ off_w,
                                              const float* __restrict__ off_b,
                                              unsigned short* __restrict__ xpb,
                                              float* __restrict__ offs0,
                                              float* __restrict__ offs1) {
  __shared__ unsigned short As[2][32 * 40];    // [pix][k] dbuf
  __shared__ unsigned short Bs[2][128 * 40];   // [n][k] dbuf; Bs[0] reused as Cs

  // XCD-aligned decode: g -> (e, nh, b, m); both ch-halves of a strip share e
  int g    = blockIdx.x;         // 0..1151
  int e    = g & 7;
  int idx  = g >> 3;             // 0..143
  int nh   = idx & 1;            // channel half
  int idx2 = idx >> 1;           // 0..71
  int b    = idx2 / 36;
  int m    = idx2 - b * 36;      // 0..35
  int pix0 = (e * 36 + m) * 32;  // local pixel within batch
  int nb0  = nh * 128;           // output-channel base

  int t    = threadIdx.x;
  int lane = t & 63;
  int w    = t >> 6;
  int mw  = (w & 1) * 16;        // wave pixel tile
  int nwl = (w >> 1) * 64;       // wave channel quarter (of 128)
  int r = lane & 15, q = lane >> 4;

  f32x4 acc[4] = {};

  const float* xg = x + (size_t)b * CC * HWP + pix0;
  int sc = t >> 3;           // channel within 32-chunk
  int sp = (t & 7) * 4;      // pixel offset
  int nB = t >> 1;           // B row (0..127)
  int kh = (t & 1) * 16;     // B k-offset

  // ---- prologue: stage K-step 0 into buf 0 (B converted inline from f32)
  {
    f32x4 xv = *(const f32x4*)(xg + (size_t)sc * HWP + sp);
    As[0][(sp + 0) * 40 + sc] = f2bf(xv.x);
    As[0][(sp + 1) * 40 + sc] = f2bf(xv.y);
    As[0][(sp + 2) * 40 + sc] = f2bf(xv.z);
    As[0][(sp + 3) * 40 + sc] = f2bf(xv.w);
    const float* wp = pw_w + (size_t)(nb0 + nB) * 256 + kh;
#pragma unroll
    for (int h = 0; h < 2; ++h) {
      float4 w0 = *(const float4*)(wp + h * 8);
      float4 w1 = *(const float4*)(wp + h * 8 + 4);
      union { ushort4 s[2]; uint4 q4; } pk;
      pk.s[0] = make_ushort4(f2bf(w0.x), f2bf(w0.y), f2bf(w0.z), f2bf(w0.w));
      pk.s[1] = make_ushort4(f2bf(w1.x), f2bf(w1.y), f2bf(w1.z), f2bf(w1.w));
      *(uint4*)&Bs[0][nB * 40 + kh + h * 8] = pk.q4;
    }
  }
  __syncthreads();

  // ---- main loop: 1 barrier per K-step, prefetch t+1 overlapped with MFMA(t)
  for (int kt = 0; kt < 8; ++kt) {
    int cur = kt & 1;
    f32x4 xv;
    float4 b0[2], b1[2];
    bool pre = (kt < 7);
    if (pre) {
      int k0 = (kt + 1) * 32;
      xv = *(const f32x4*)(xg + (size_t)(k0 + sc) * HWP + sp);
      const float* wp = pw_w + (size_t)(nb0 + nB) * 256 + k0 + kh;
#pragma unroll
      for (int h = 0; h < 2; ++h) {
        b0[h] = *(const float4*)(wp + h * 8);
        b1[h] = *(const float4*)(wp + h * 8 + 4);
      }
    }
    bf16x8 a = *(const bf16x8*)&As[cur][(mw + r) * 40 + q * 8];
#pragma unroll
    for (int nt = 0; nt < 4; ++nt) {
      bf16x8 bb = *(const bf16x8*)&Bs[cur][(nwl + nt * 16 + r) * 40 + q * 8];
      acc[nt] = __builtin_amdgcn_mfma_f32_16x16x32_bf16(a, bb, acc[nt], 0, 0, 0);
    }
    if (pre) {
      int nx = cur ^ 1;
      As[nx][(sp + 0) * 40 + sc] = f2bf(xv.x);
      As[nx][(sp + 1) * 40 + sc] = f2bf(xv.y);
      As[nx][(sp + 2) * 40 + sc] = f2bf(xv.z);
      As[nx][(sp + 3) * 40 + sc] = f2bf(xv.w);
#pragma unroll
      for (int h = 0; h < 2; ++h) {
        union { ushort4 s[2]; uint4 q4; } pk;
        pk.s[0] = make_ushort4(f2bf(b0[h].x), f2bf(b0[h].y), f2bf(b0[h].z), f2bf(b0[h].w));
        pk.s[1] = make_ushort4(f2bf(b1[h].x), f2bf(b1[h].y), f2bf(b1[h].z), f2bf(b1[h].w));
        *(uint4*)&Bs[nx][nB * 40 + kh + h * 8] = pk.q4;
      }
    }
    __syncthreads();
  }

  // Cs aliases Bs[0]: last K-step read buf 1; final sync drained buf 0 reads.
  unsigned short* Cs = &Bs[0][0];   // [32][136] bf16 (4352 shorts <= 5120)

  // C/D: col = lane&15 (ch), row = q*4+rr (pix) -> Cs[pix][ch] bf16
#pragma unroll
  for (int nt = 0; nt < 4; ++nt)
#pragma unroll
    for (int rr = 0; rr < 4; ++rr)
      Cs[(mw + q * 4 + rr) * 136 + nwl + nt * 16 + r] = f2bf(acc[nt][rr]);
  __syncthreads();

  // write xpb coalesced: 32 B contiguous per thread (128-ch half)
  {
    int pix = t >> 3, c16 = (t & 7) * 16;
    unsigned short* o = xpb + ((size_t)b * HWP + pix0 + pix) * CC + nb0 + c16;
    *(uint4*)(o + 0) = *(const uint4*)&Cs[pix * 136 + c16 + 0];
    *(uint4*)(o + 8) = *(const uint4*)&Cs[pix * 136 + c16 + 8];
  }

  // offs PARTIAL epilogue over this block's K=128 slice (4 K-steps):
  // offs_h[pix, o] = sum_{c in half} Cs[pix][c] * off_w[o][nb0+c] (+off_b if nh==0)
  {
    float* offs_h = nh ? offs1 : offs0;
    int mw2 = (w & 1) * 16;    // pixel tile
    int nw2 = (w >> 1) * 16;   // o tile (0 or 16)
    int row = nw2 + r;
    f32x4 oacc = {};
#pragma unroll
    for (int ks = 0; ks < 128; ks += 32) {
      bf16x8 a = *(const bf16x8*)&Cs[(mw2 + r) * 136 + ks + q * 8];
      bf16x8 bb = {};
      if (row < 18) {
        const float* wp = off_w + row * 256 + nb0 + ks + q * 8;
        float4 w0 = *(const float4*)wp;
        float4 w1 = *(const float4*)(wp + 4);
        union { unsigned short u[8]; bf16x8 v; } pk;
        pk.u[0] = f2bf(w0.x); pk.u[1] = f2bf(w0.y); pk.u[2] = f2bf(w0.z); pk.u[3] = f2bf(w0.w);
        pk.u[4] = f2bf(w1.x); pk.u[5] = f2bf(w1.y); pk.u[6] = f2bf(w1.z); pk.u[7] = f2bf(w1.w);
        bb = pk.v;
      }
      oacc = __builtin_amdgcn_mfma_f32_16x16x32_bf16(a, bb, oacc, 0, 0, 0);
    }
    if (row < 18) {
      float ob = nh ? 0.f : off_b[row];
      size_t base = ((size_t)b * HWP + pix0 + mw2 + q * 4) * 20 + row;
#pragma unroll
      for (int rr = 0; rr < 4; ++rr)
        offs_h[base + (size_t)rr * 20] = oacc[rr] + ob;
    }
  }
}

// ---- gather + depthwise: R18/R19 structure (8 px/block, half-wave pixel
// split, uint4 corner loads, padc LDS, block-barrier decode). R22: offs
// loads hoisted above dvs staging (latency overlap only; same math).
__global__ __launch_bounds__(256) void k_gather(const unsigned short* __restrict__ xp,
                                                const float* __restrict__ offs0,
                                                const float* __restrict__ offs1,
                                                const float* __restrict__ dw_w,
                                                float* __restrict__ out) {
  __shared__ float Cs[8][268];    // padc-padded (256 + 12)
  __shared__ float4 Wt[8][9];     // bilinear weights per (pixel, tap)
  __shared__ int4   Ad[8][9];     // corner row byte-offsets per (pixel, tap)
  __shared__ float  dvs[9][268];  // dw_w transposed [tap][ch], padc-padded

  // XCD-aligned decode: g -> (e, b, m2); chunk c = e*144 + m2 (8 px each)
  int g   = blockIdx.x;          // 0..2303
  int e   = g & 7;
  int idx = g >> 3;              // 0..287
  int b   = idx / 144;
  int m2  = idx - b * 144;       // 0..143
  int c   = e * 144 + m2;        // 0..1151
  int hw0 = c * 8;               // pixel within batch
  int pix0 = b * HWP + hw0;      // global pixel

  int wave = threadIdx.x >> 6;
  int lane = threadIdx.x & 63;
  int hp   = lane >> 5;          // half-wave pixel select (0/1)
  int hl   = lane & 31;          // lane within half-wave
  int ip   = wave * 2 + hp;      // this lane's pixel 0..7
  int c0   = hl * 8;             // this lane's 8-channel base
  int pc0  = padc(c0);           // padded LDS index (16B-aligned)

  const unsigned short* xb = xp + (size_t)b * HWP * CC;
  const float* opb0 = offs0 + (size_t)pix0 * 20;
  const float* opb1 = offs1 + (size_t)pix0 * 20;

  // ---- R22 hoist: issue offs loads for the decode (tp<72) FIRST so their
  // L2 latency overlaps the dvs staging below. Same values, same consumers.
  int tp = threadIdx.x;
  int ipp = tp / 9;              // pixel 0..7 (valid when tp<72)
  int kkd = tp - ipp * 9;        // tap 0..8
  float2 oa = make_float2(0.f, 0.f), ob2 = make_float2(0.f, 0.f);
  if (tp < 72) {
    oa  = *(const float2*)(opb0 + ipp * 20 + 2 * kkd);
    ob2 = *(const float2*)(opb1 + ipp * 20 + 2 * kkd);
  }

  // ---- phase 0a: stage dw_w transposed (9 scalar loads/thread)
  {
    int t = threadIdx.x;
    int pt = padc(t);
#pragma unroll
    for (int kk = 0; kk < 9; ++kk)
      dvs[kk][pt] = dw_w[t * 9 + kk];
  }

  // ---- phase 0b: 72 threads compute the wave-uniform per-(pixel,tap) data
  if (tp < 72) {
    int kk = kkd;
    int hw = hw0 + ipp;
    int h = hw / WW;
    int wq = hw - h * WW;
    float y = (float)(h + kk / 3 - 1) + oa.x + ob2.x;
    float x = (float)(wq + kk % 3 - 1) + oa.y + ob2.y;
    float y0f = floorf(y), x0f = floorf(x);
    float fy = y - y0f, fx = x - x0f;
    int y0 = (int)y0f, x0 = (int)x0f;
    int y1 = y0 + 1, x1 = x0 + 1;
    bool vy0 = (y0 >= 0) & (y0 < HH);
    bool vy1 = (y1 >= 0) & (y1 < HH);
    bool vx0 = (x0 >= 0) & (x0 < WW);
    bool vx1 = (x1 >= 0) & (x1 < WW);
    int y0c = y0 < 0 ? 0 : (y0 > HH - 1 ? HH - 1 : y0);
    int y1c = y1 < 0 ? 0 : (y1 > HH - 1 ? HH - 1 : y1);
    int x0c = x0 < 0 ? 0 : (x0 > WW - 1 ? WW - 1 : x0);
    int x1c = x1 < 0 ? 0 : (x1 > WW - 1 ? WW - 1 : x1);
    Wt[ipp][kk] = make_float4(
        (1.f - fy) * (1.f - fx) * ((vy0 && vx0) ? 1.f : 0.f),
        (1.f - fy) * fx         * ((vy0 && vx1) ? 1.f : 0.f),
        fy * (1.f - fx)         * ((vy1 && vx0) ? 1.f : 0.f),
        fy * fx                 * ((vy1 && vx1) ? 1.f : 0.f));
    Ad[ipp][kk] = make_int4((y0c * WW + x0c) * (CC * 2), (y0c * WW + x1c) * (CC * 2),
                            (y1c * WW + x0c) * (CC * 2), (y1c * WW + x1c) * (CC * 2));
  }
  __syncthreads();

  // ---- main loop: 4 uint4 corner loads per tap; unpack + FMA only.
  const char* xbc = (const char*)xb;
  unsigned lb = (unsigned)(hl * 16);   // this lane's 8-channel byte offset

  float acc[8] = {};
#pragma unroll
  for (int kk = 0; kk < 9; ++kk) {
    float4 dv0 = *(const float4*)&dvs[kk][pc0];
    float4 dv1 = *(const float4*)&dvs[kk][pc0 + 4];
    float4 wv = Wt[ip][kk];
    int4 av = Ad[ip][kk];
    uint4 u00 = *(const uint4*)(xbc + ((unsigned)av.x + lb));
    uint4 u01 = *(const uint4*)(xbc + ((unsigned)av.y + lb));
    uint4 u10 = *(const uint4*)(xbc + ((unsigned)av.z + lb));
    uint4 u11 = *(const uint4*)(xbc + ((unsigned)av.w + lb));
    const unsigned* p00 = (const unsigned*)&u00;
    const unsigned* p01 = (const unsigned*)&u01;
    const unsigned* p10 = (const unsigned*)&u10;
    const unsigned* p11 = (const unsigned*)&u11;
    float dvv[8] = {dv0.x, dv0.y, dv0.z, dv0.w, dv1.x, dv1.y, dv1.z, dv1.w};
#pragma unroll
    for (int j = 0; j < 4; ++j) {
      unsigned w00 = p00[j], w01 = p01[j], w10 = p10[j], w11 = p11[j];
      float slo = wv.x * bf_lo(w00) + wv.y * bf_lo(w01) + wv.z * bf_lo(w10) + wv.w * bf_lo(w11);
      float shi = wv.x * bf_hi(w00) + wv.y * bf_hi(w01) + wv.z * bf_hi(w10) + wv.w * bf_hi(w11);
      acc[2 * j]     += dvv[2 * j]     * slo;
      acc[2 * j + 1] += dvv[2 * j + 1] * shi;
    }
  }
  *(float4*)&Cs[ip][pc0]     = make_float4(acc[0], acc[1], acc[2], acc[3]);
  *(float4*)&Cs[ip][pc0 + 4] = make_float4(acc[4], acc[5], acc[6], acc[7]);
  __syncthreads();
  // write-out: thread t = channel, 8 consecutive pixels = 32 B contiguous.
  int ch = threadIdx.x;
  int pch = padc(ch);
  float* ob = out + (size_t)b * CC * HWP + (size_t)ch * HWP + hw0;
  *(float4*)(ob + 0) = make_float4(Cs[0][pch], Cs[1][pch], Cs[2][pch], Cs[3][pch]);
  *(float4*)(ob + 4) = make_float4(Cs[4][pch], Cs[5][pch], Cs[6][pch], Cs[7][pch]);
}

extern "C" void kernel_launch(void* const* d_in, const int* in_sizes, int n_in,
                              void* d_out, int out_size, void* d_ws, size_t ws_size,
                              hipStream_t stream) {
  (void)in_sizes; (void)n_in; (void)out_size; (void)ws_size;
  const float* x     = (const float*)d_in[0];
  const float* pw_w  = (const float*)d_in[1];
  const float* off_w = (const float*)d_in[2];
  const float* off_b = (const float*)d_in[3];
  const float* dw_w  = (const float*)d_in[4];
  float* out = (float*)d_out;

  char* ws = (char*)d_ws;
  unsigned short* xpb = (unsigned short*)ws;             // B*HW*C bf16 = 9,437,184 B
  float* offs0 = (float*)(ws + 9437184);                 // B*HW*20 f32 = 1,474,560 B
  float* offs1 = (float*)(ws + 10911744);                // B*HW*20 f32 = 1,474,560 B

  k_main  <<<1152, 256, 0, stream>>>(x, pw_w, off_w, off_b, xpb, offs0, offs1);
  k_gather<<<2304, 256, 0, stream>>>(xpb, offs0, offs1, dw_w, out);
}